// Round 1
// baseline (189.929 us; speedup 1.0000x reference)
//
#include <hip/hip_runtime.h>
#include <math.h>
#include <stdint.h>

#define S_N 2048
#define X_N 2048
#define G_N 2
#define F_N 3072

// GEMM tile: 256(M) x 128(N), BK=64, 512 threads = 8 waves (4M x 2N, 64x64 each)
#define TM 256
#define TN 128
#define BK 64
#define ITERS (F_N / BK)  // 48
#define NBUF 3            // triple buffer: no WAR hazard, no vmcnt(0) drain in loop

typedef __bf16 bf16;
typedef __bf16 bf16x4 __attribute__((ext_vector_type(4)));
typedef __bf16 bf16x8 __attribute__((ext_vector_type(8)));
typedef float f32x4 __attribute__((ext_vector_type(4)));
typedef int i32x4 __attribute__((ext_vector_type(4)));

// async global->LDS, 16B per lane; LDS dest = wave-uniform base + lane*16
__device__ __forceinline__ void gload_lds16(const bf16* g, void* l) {
  __builtin_amdgcn_global_load_lds(
      (const __attribute__((address_space(1))) void*)g,
      (__attribute__((address_space(3))) void*)l, 16, 0, 0);
}

// ---------------- P0a: const[g] + rinv[g,f] = 1/std ----
__global__ void k_const(const float* __restrict__ stdv, float* __restrict__ constg,
                        float* __restrict__ rinv) {
  int g = blockIdx.x;
  int t = threadIdx.x;
  float s = 0.f;
  for (int f = t; f < F_N; f += 256) {
    float v = stdv[g * F_N + f];
    rinv[g * F_N + f] = 1.0f / v;
    s += logf(v);
  }
  for (int o = 32; o; o >>= 1) s += __shfl_xor(s, o);
  __shared__ float red[4];
  int w = t >> 6, l = t & 63;
  if (l == 0) red[w] = s;
  __syncthreads();
  if (t == 0) {
    float tot = red[0] + red[1] + red[2] + red[3];
    constg[g] = -0.5f * (float)F_N * 1.8378770664093453f - tot;
  }
}

// ---------------- P0b: u = s*rinv_g (bf16) + A[g,s]=||u||^2 ; same for x->v,C
__global__ void k_prep(const float* __restrict__ samples, const float* __restrict__ xin,
                       const float* __restrict__ rinv,
                       bf16* __restrict__ U, bf16* __restrict__ V,
                       float* __restrict__ A, float* __restrict__ C) {
  int r = blockIdx.x;
  int t = threadIdx.x;
  bool isS = (r < S_N);
  const float* src = isS ? (samples + (size_t)r * F_N) : (xin + (size_t)(r - S_N) * F_N);
  float4 row[3];
#pragma unroll
  for (int j = 0; j < 3; ++j) row[j] = ((const float4*)src)[t + j * 256];

  __shared__ float red[4];
  int w = t >> 6, l = t & 63;

  for (int g = 0; g < G_N; ++g) {
    const float4* sd = (const float4*)(rinv + (size_t)g * F_N);
    bf16* dst = isS ? (U + ((size_t)g * S_N + r) * F_N)
                    : (V + ((size_t)g * X_N + (r - S_N)) * F_N);
    float acc = 0.f;
#pragma unroll
    for (int j = 0; j < 3; ++j) {
      float4 d = sd[t + j * 256];
      float u0 = row[j].x * d.x;
      float u1 = row[j].y * d.y;
      float u2 = row[j].z * d.z;
      float u3 = row[j].w * d.w;
      bf16x4 b;
      b[0] = (bf16)u0; b[1] = (bf16)u1; b[2] = (bf16)u2; b[3] = (bf16)u3;
      float f0 = (float)b[0], f1 = (float)b[1], f2 = (float)b[2], f3 = (float)b[3];
      acc += f0 * f0 + f1 * f1 + f2 * f2 + f3 * f3;
      ((bf16x4*)dst)[t + j * 256] = b;
    }
    for (int o = 32; o; o >>= 1) acc += __shfl_xor(acc, o);
    __syncthreads();
    if (l == 0) red[w] = acc;
    __syncthreads();
    if (t == 0) {
      float tot = red[0] + red[1] + red[2] + red[3];
      if (isS) A[(size_t)g * S_N + r] = tot;
      else     C[(size_t)g * X_N + (r - S_N)] = tot;
    }
  }
}

// ---------------- P1: logits[g,s,x] = (u v^T)[s,x] - 0.5*(A[g,s]+C[g,x]) ----
// 256x128 tile, BK=64, 512 thr (8 waves 4Mx2N of 64x64). Triple-buffered LDS
// (144 KiB), global_load_lds width-16 staging with inverse-swizzled global
// source (linear LDS dest), swizzled ds_read_b128 (f(row)=(row>>1)&7, 0
// conflicts). 2 phases per K-tile, 16 MFMA each, counted vmcnt(6) once per
// K-tile (6 loads/tile/thread, 2 tiles in flight) — never vmcnt(0) in loop.
__global__ __launch_bounds__(512, 2) void k_gemm(const bf16* __restrict__ U, const bf16* __restrict__ V,
                                                 const float* __restrict__ A, const float* __restrict__ C,
                                                 float* __restrict__ logits) {
  __shared__ i32x4 ldsA[NBUF][TM * BK / 8];  // 3 x 2048 x 16B = 96 KB
  __shared__ i32x4 ldsB[NBUF][TN * BK / 8];  // 3 x 1024 x 16B = 48 KB

  int t = threadIdx.x;
  int g = blockIdx.z;
  int bm = blockIdx.y * TM;
  int bn = blockIdx.x * TN;

  const bf16* Ub = U + ((size_t)g * S_N + bm) * F_N;
  const bf16* Vb = V + ((size_t)g * X_N + bn) * F_N;

  int wave = t >> 6, lane = t & 63;
  int wm = wave & 3, wn = wave >> 2;   // 4x2 waves, 64x64 each
  int r = lane & 15, q = lane >> 4;
  int fr = (r >> 1) & 7;               // 3-bit read swizzle
  int ck0 = q ^ fr;                    // slot chunk for ks=0
  int ck1 = (4 | q) ^ fr;              // slot chunk for ks=1
  int abase = (wm * 64 + r) * 8;
  int bbase = (wn * 64 + r) * 8;

  // Staging: slot s = t + j*512 holds global chunk (row=s>>3, (s&7)^((s>>4)&7)).
  // gcc is j-invariant since 512>>4 = 32 ≡ 0 (mod 8).
  int row0 = t >> 3;                   // 0..63
  int gcc = (t & 7) ^ ((t >> 4) & 7);
  const bf16* gA[4];
  const bf16* gB[2];
#pragma unroll
  for (int j = 0; j < 4; ++j) gA[j] = Ub + (size_t)(row0 + j * 64) * F_N + gcc * 8;
#pragma unroll
  for (int j = 0; j < 2; ++j) gB[j] = Vb + (size_t)(row0 + j * 64) * F_N + gcc * 8;

  f32x4 acc[4][4] = {};

  // prologue: tile0 -> buf0, tile1 -> buf1; wait tile0 (6 of 12 outstanding)
#pragma unroll
  for (int j = 0; j < 4; ++j) gload_lds16(gA[j], &ldsA[0][t + j * 512]);
#pragma unroll
  for (int j = 0; j < 2; ++j) gload_lds16(gB[j], &ldsB[0][t + j * 512]);
#pragma unroll
  for (int j = 0; j < 4; ++j) gload_lds16(gA[j] + BK, &ldsA[1][t + j * 512]);
#pragma unroll
  for (int j = 0; j < 2; ++j) gload_lds16(gB[j] + BK, &ldsB[1][t + j * 512]);
  asm volatile("s_waitcnt vmcnt(6)" ::: "memory");
  __builtin_amdgcn_s_barrier();

  int cur = 0;
  for (int it = 0; it < ITERS; ++it) {
    int k2 = it + 2;
    int pk = (k2 < ITERS ? k2 : 0) * BK;  // clamped: uniform vmcnt math in tail
    int stg = (cur >= 1) ? cur - 1 : 2;   // (cur+2)%3 — tile it+2's buffer
    const i32x4* LA = ldsA[cur];
    const i32x4* LB = ldsB[cur];

    // ---- phase 0: stage 3/6 of tile it+2; ds_read af[all]+b[0..1]; MFMA ni=0,1
    gload_lds16(gA[0] + pk, &ldsA[stg][t]);
    gload_lds16(gA[1] + pk, &ldsA[stg][t + 512]);
    gload_lds16(gA[2] + pk, &ldsA[stg][t + 1024]);
    bf16x8 af[4][2], b01[2][2];
#pragma unroll
    for (int mi = 0; mi < 4; ++mi) {
      af[mi][0] = __builtin_bit_cast(bf16x8, LA[abase + mi * 128 + ck0]);
      af[mi][1] = __builtin_bit_cast(bf16x8, LA[abase + mi * 128 + ck1]);
    }
#pragma unroll
    for (int ni = 0; ni < 2; ++ni) {
      b01[ni][0] = __builtin_bit_cast(bf16x8, LB[bbase + ni * 128 + ck0]);
      b01[ni][1] = __builtin_bit_cast(bf16x8, LB[bbase + ni * 128 + ck1]);
    }
    __builtin_amdgcn_s_barrier();
    asm volatile("s_waitcnt lgkmcnt(0)" ::: "memory");
    __builtin_amdgcn_sched_barrier(0);  // rule 18: keep MFMA below the wait
    __builtin_amdgcn_s_setprio(1);
#pragma unroll
    for (int ks = 0; ks < 2; ++ks)
#pragma unroll
      for (int mi = 0; mi < 4; ++mi)
#pragma unroll
        for (int ni = 0; ni < 2; ++ni)
          acc[mi][ni] = __builtin_amdgcn_mfma_f32_16x16x32_bf16(af[mi][ks], b01[ni][ks], acc[mi][ni], 0, 0, 0);
    __builtin_amdgcn_s_setprio(0);
    __builtin_amdgcn_s_barrier();

    // ---- phase 1: stage 3/6; ds_read b[2..3]; counted vmcnt; MFMA ni=2,3
    gload_lds16(gA[3] + pk, &ldsA[stg][t + 1536]);
    gload_lds16(gB[0] + pk, &ldsB[stg][t]);
    gload_lds16(gB[1] + pk, &ldsB[stg][t + 512]);
    bf16x8 b23[2][2];
#pragma unroll
    for (int ni = 0; ni < 2; ++ni) {
      b23[ni][0] = __builtin_bit_cast(bf16x8, LB[bbase + (2 + ni) * 128 + ck0]);
      b23[ni][1] = __builtin_bit_cast(bf16x8, LB[bbase + (2 + ni) * 128 + ck1]);
    }
    // outstanding: tile it+1 (6, oldest) + tile it+2 (6) -> wait it+1 landed
    asm volatile("s_waitcnt vmcnt(6)" ::: "memory");
    __builtin_amdgcn_s_barrier();
    asm volatile("s_waitcnt lgkmcnt(0)" ::: "memory");
    __builtin_amdgcn_sched_barrier(0);
    __builtin_amdgcn_s_setprio(1);
#pragma unroll
    for (int ks = 0; ks < 2; ++ks)
#pragma unroll
      for (int mi = 0; mi < 4; ++mi)
#pragma unroll
        for (int ni = 0; ni < 2; ++ni)
          acc[mi][2 + ni] = __builtin_amdgcn_mfma_f32_16x16x32_bf16(af[mi][ks], b23[ni][ks], acc[mi][2 + ni], 0, 0, 0);
    __builtin_amdgcn_s_setprio(0);
    __builtin_amdgcn_s_barrier();

    cur = (cur == 2) ? 0 : cur + 1;
  }

  // Epilogue: C/D layout col=lane&15, row=(lane>>4)*4+reg
  const float* Ap = A + (size_t)g * S_N + bm + wm * 64;
  const float* Cp = C + (size_t)g * X_N + bn + wn * 64;
  float cv[4];
#pragma unroll
  for (int ni = 0; ni < 4; ++ni) cv[ni] = Cp[ni * 16 + r];
#pragma unroll
  for (int mi = 0; mi < 4; ++mi) {
#pragma unroll
    for (int i = 0; i < 4; ++i) {
      int rowl = wm * 64 + mi * 16 + q * 4 + i;
      float av = Ap[mi * 16 + q * 4 + i];
      float* orow = logits + ((size_t)g * S_N + bm + rowl) * X_N + bn + wn * 64;
#pragma unroll
      for (int ni = 0; ni < 4; ++ni)
        orow[ni * 16 + r] = acc[mi][ni][i] - 0.5f * (av + cv[ni]);
    }
  }
}

// ---------------- P2: out[s] = LSE over (g,x) of (logits + const[g]) - log(X*G)
__global__ void k_lse(const float* __restrict__ logits, const float* __restrict__ constg,
                      float* __restrict__ out) {
  int s = blockIdx.x, t = threadIdx.x;
  float c0 = constg[0], c1 = constg[1];
  const float4* p0 = (const float4*)(logits + (size_t)s * X_N);
  const float4* p1 = (const float4*)(logits + ((size_t)S_N + s) * X_N);
  float4 v[4];
  v[0] = p0[t]; v[1] = p0[t + 256];
  v[2] = p1[t]; v[3] = p1[t + 256];
  v[0].x += c0; v[0].y += c0; v[0].z += c0; v[0].w += c0;
  v[1].x += c0; v[1].y += c0; v[1].z += c0; v[1].w += c0;
  v[2].x += c1; v[2].y += c1; v[2].z += c1; v[2].w += c1;
  v[3].x += c1; v[3].y += c1; v[3].z += c1; v[3].w += c1;

  float m = v[0].x;
#pragma unroll
  for (int j = 0; j < 4; ++j) {
    m = fmaxf(m, v[j].x); m = fmaxf(m, v[j].y);
    m = fmaxf(m, v[j].z); m = fmaxf(m, v[j].w);
  }
  for (int o = 32; o; o >>= 1) m = fmaxf(m, __shfl_xor(m, o));
  __shared__ float redm[4];
  __shared__ float reds[4];
  int w = t >> 6, l = t & 63;
  if (l == 0) redm[w] = m;
  __syncthreads();
  m = fmaxf(fmaxf(redm[0], redm[1]), fmaxf(redm[2], redm[3]));

  float sum = 0.f;
#pragma unroll
  for (int j = 0; j < 4; ++j) {
    sum += expf(v[j].x - m) + expf(v[j].y - m) + expf(v[j].z - m) + expf(v[j].w - m);
  }
  for (int o = 32; o; o >>= 1) sum += __shfl_xor(sum, o);
  if (l == 0) reds[w] = sum;
  __syncthreads();
  if (t == 0) {
    float tot = reds[0] + reds[1] + reds[2] + reds[3];
    out[s] = m + logf(tot) - 8.317766166719343f;  // log(4096)
  }
}

extern "C" void kernel_launch(void* const* d_in, const int* in_sizes, int n_in,
                              void* d_out, int out_size, void* d_ws, size_t ws_size,
                              hipStream_t stream) {
  const float* samples = (const float*)d_in[0];  // [S, F] fp32
  const float* xin     = (const float*)d_in[1];  // [X, F] fp32
  const float* stdv    = (const float*)d_in[2];  // [G, F] fp32
  float* out = (float*)d_out;                    // [S] fp32

  char* ws = (char*)d_ws;
  size_t off = 0;
  bf16* U = (bf16*)(ws + off);        off += (size_t)G_N * S_N * F_N * 2;  // 25.2 MB
  bf16* V = (bf16*)(ws + off);        off += (size_t)G_N * X_N * F_N * 2;  // 25.2 MB
  float* logits = (float*)(ws + off); off += (size_t)G_N * S_N * X_N * 4;  // 33.6 MB
  float* A = (float*)(ws + off);      off += (size_t)G_N * S_N * 4;
  float* C = (float*)(ws + off);      off += (size_t)G_N * X_N * 4;
  float* constg = (float*)(ws + off); off += 256;
  float* rinv = (float*)(ws + off);   off += (size_t)G_N * F_N * 4;

  k_const<<<dim3(G_N), dim3(256), 0, stream>>>(stdv, constg, rinv);
  k_prep<<<dim3(S_N + X_N), dim3(256), 0, stream>>>(samples, xin, rinv, U, V, A, C);
  k_gemm<<<dim3(X_N / TN, S_N / TM, G_N), dim3(512), 0, stream>>>(U, V, A, C, logits);
  k_lse<<<dim3(S_N), dim3(256), 0, stream>>>(logits, constg, out);
}

// Round 2
// 155.912 us; speedup vs baseline: 1.2182x; 1.2182x over previous
//
#include <hip/hip_runtime.h>
#include <math.h>
#include <stdint.h>

#define S_N 2048
#define X_N 2048
#define G_N 2
#define F_N 3072

// GEMM tile: 256(M) x 128(N), BK=64, 512 threads = 8 waves.
// 4 wave-positions of 128x64 output; 2 waves per position split the K-tile
// (wave kh=0 takes k-chunks 0..3, kh=1 takes 4..7 of each BK=64 tile),
// pair-summed through LDS scratch in the epilogue.
#define TM 256
#define TN 128
#define BK 64
#define ITERS (F_N / BK)  // 48
#define NBUF 3            // triple buffer: no WAR hazard, no vmcnt(0) drain in loop

typedef __bf16 bf16;
typedef __bf16 bf16x4 __attribute__((ext_vector_type(4)));
typedef __bf16 bf16x8 __attribute__((ext_vector_type(8)));
typedef float f32x4 __attribute__((ext_vector_type(4)));
typedef int i32x4 __attribute__((ext_vector_type(4)));

// async global->LDS, 16B per lane; LDS dest = wave-uniform base + lane*16
__device__ __forceinline__ void gload_lds16(const bf16* g, void* l) {
  __builtin_amdgcn_global_load_lds(
      (const __attribute__((address_space(1))) void*)g,
      (__attribute__((address_space(3))) void*)l, 16, 0, 0);
}

// ---------------- P0a: const[g] + rinv[g,f] = 1/std ----
__global__ void k_const(const float* __restrict__ stdv, float* __restrict__ constg,
                        float* __restrict__ rinv) {
  int g = blockIdx.x;
  int t = threadIdx.x;
  float s = 0.f;
  for (int f = t; f < F_N; f += 256) {
    float v = stdv[g * F_N + f];
    rinv[g * F_N + f] = 1.0f / v;
    s += logf(v);
  }
  for (int o = 32; o; o >>= 1) s += __shfl_xor(s, o);
  __shared__ float red[4];
  int w = t >> 6, l = t & 63;
  if (l == 0) red[w] = s;
  __syncthreads();
  if (t == 0) {
    float tot = red[0] + red[1] + red[2] + red[3];
    constg[g] = -0.5f * (float)F_N * 1.8378770664093453f - tot;
  }
}

// ---------------- P0b: u = s*rinv_g (bf16) + A[g,s]=||u||^2 ; same for x->v,C
__global__ void k_prep(const float* __restrict__ samples, const float* __restrict__ xin,
                       const float* __restrict__ rinv,
                       bf16* __restrict__ U, bf16* __restrict__ V,
                       float* __restrict__ A, float* __restrict__ C) {
  int r = blockIdx.x;
  int t = threadIdx.x;
  bool isS = (r < S_N);
  const float* src = isS ? (samples + (size_t)r * F_N) : (xin + (size_t)(r - S_N) * F_N);
  float4 row[3];
#pragma unroll
  for (int j = 0; j < 3; ++j) row[j] = ((const float4*)src)[t + j * 256];

  __shared__ float red[4];
  int w = t >> 6, l = t & 63;

  for (int g = 0; g < G_N; ++g) {
    const float4* sd = (const float4*)(rinv + (size_t)g * F_N);
    bf16* dst = isS ? (U + ((size_t)g * S_N + r) * F_N)
                    : (V + ((size_t)g * X_N + (r - S_N)) * F_N);
    float acc = 0.f;
#pragma unroll
    for (int j = 0; j < 3; ++j) {
      float4 d = sd[t + j * 256];
      float u0 = row[j].x * d.x;
      float u1 = row[j].y * d.y;
      float u2 = row[j].z * d.z;
      float u3 = row[j].w * d.w;
      bf16x4 b;
      b[0] = (bf16)u0; b[1] = (bf16)u1; b[2] = (bf16)u2; b[3] = (bf16)u3;
      float f0 = (float)b[0], f1 = (float)b[1], f2 = (float)b[2], f3 = (float)b[3];
      acc += f0 * f0 + f1 * f1 + f2 * f2 + f3 * f3;
      ((bf16x4*)dst)[t + j * 256] = b;
    }
    for (int o = 32; o; o >>= 1) acc += __shfl_xor(acc, o);
    __syncthreads();
    if (l == 0) red[w] = acc;
    __syncthreads();
    if (t == 0) {
      float tot = red[0] + red[1] + red[2] + red[3];
      if (isS) A[(size_t)g * S_N + r] = tot;
      else     C[(size_t)g * X_N + (r - S_N)] = tot;
    }
  }
}

// ---------------- P1: logits[g,s,x] = (u v^T)[s,x] - 0.5*(A[g,s]+C[g,x]) ----
// 256x128 tile, BK=64, 512 thr. 8 waves = 4 positions (2M x 2N) of 128x64,
// x2 waves/position splitting each K-tile in half (kh = wave&1).
// Per wave per K-tile: 12 ds_read_b128 for 32 MFMA (DS:MFMA cycle ratio 0.93,
// balanced). Triple-buffered LDS (144 KiB), global_load_lds width-16 with
// inverse-swizzled global source (linear LDS dest), swizzled ds_read_b128
// (f(row)=(row>>1)&7, measured 0 conflicts). Counted vmcnt(6) once per K-tile
// (6 loads/tile/thread, 2 tiles in flight) — never vmcnt(0) in main loop.
// Epilogue: pair-sum via LDS scratch half-exchange, then store.
__global__ __launch_bounds__(512, 2) void k_gemm(const bf16* __restrict__ U, const bf16* __restrict__ V,
                                                 const float* __restrict__ A, const float* __restrict__ C,
                                                 float* __restrict__ logits) {
  // [0, 6144): ldsA (3 bufs x 2048 slots); [6144, 9216): ldsB (3 x 1024). 144 KiB.
  __shared__ i32x4 lds[NBUF * 2048 + NBUF * 1024];
  i32x4* ldsA = lds;
  i32x4* ldsB = lds + NBUF * 2048;

  int t = threadIdx.x;
  int g = blockIdx.z;
  int bm = blockIdx.y * TM;
  int bn = blockIdx.x * TN;

  const bf16* Ub = U + ((size_t)g * S_N + bm) * F_N;
  const bf16* Vb = V + ((size_t)g * X_N + bn) * F_N;

  int wave = t >> 6, lane = t & 63;
  int pos = wave >> 1;                 // 0..3: output position
  int kh = wave & 1;                   // K-half of each BK=64 tile
  int wm = pos >> 1;                   // A rows: wm*128
  int wn = pos & 1;                    // B rows: wn*64
  int r = lane & 15, q = lane >> 4;
  int fr = (r >> 1) & 7;               // 3-bit read swizzle
  int ck = (kh * 4 + q) ^ fr;          // chunk-in-row for this wave's K-half
  int abase = (wm * 128 + r) * 8;
  int bbase = (wn * 64 + r) * 8;

  // Staging: slot s = t + j*512 holds global chunk (row=s>>3, (s&7)^((s>>4)&7)).
  // gcc is j-invariant since 512>>4 = 32 ≡ 0 (mod 8).
  int row0 = t >> 3;                   // 0..63
  int gcc = (t & 7) ^ ((t >> 4) & 7);
  const bf16* gA[4];
  const bf16* gB[2];
#pragma unroll
  for (int j = 0; j < 4; ++j) gA[j] = Ub + (size_t)(row0 + j * 64) * F_N + gcc * 8;
#pragma unroll
  for (int j = 0; j < 2; ++j) gB[j] = Vb + (size_t)(row0 + j * 64) * F_N + gcc * 8;

  f32x4 acc[8][4] = {};

  // prologue: tile0 -> buf0, tile1 -> buf1 (6 loads each, A then B order)
#pragma unroll
  for (int j = 0; j < 4; ++j) gload_lds16(gA[j], &ldsA[0 * 2048 + t + j * 512]);
#pragma unroll
  for (int j = 0; j < 2; ++j) gload_lds16(gB[j], &ldsB[0 * 1024 + t + j * 512]);
#pragma unroll
  for (int j = 0; j < 4; ++j) gload_lds16(gA[j] + BK, &ldsA[1 * 2048 + t + j * 512]);
#pragma unroll
  for (int j = 0; j < 2; ++j) gload_lds16(gB[j] + BK, &ldsB[1 * 1024 + t + j * 512]);
  asm volatile("s_waitcnt vmcnt(6)" ::: "memory");
  __builtin_amdgcn_s_barrier();

  int cur = 0;
  for (int it = 0; it < ITERS; ++it) {
    int k2 = it + 2;
    int pk = (k2 < ITERS ? k2 : 0) * BK;  // clamped: uniform vmcnt math in tail
    int stg = (cur >= 1) ? cur - 1 : 2;   // (cur+2)%3 — tile it+2's buffer
    const i32x4* LA = ldsA + cur * 2048;
    const i32x4* LB = ldsB + cur * 1024;

    bf16x8 af[4], bfr[4];

    // ---- phase 0: stage 3/6 of tile it+2; read bfr[0..3] + af[0..3]; MFMA mi 0..3
    gload_lds16(gA[0] + pk, &ldsA[stg * 2048 + t]);
    gload_lds16(gA[1] + pk, &ldsA[stg * 2048 + t + 512]);
    gload_lds16(gA[2] + pk, &ldsA[stg * 2048 + t + 1024]);
#pragma unroll
    for (int ni = 0; ni < 4; ++ni)
      bfr[ni] = __builtin_bit_cast(bf16x8, LB[bbase + ni * 128 + ck]);
#pragma unroll
    for (int mi = 0; mi < 4; ++mi)
      af[mi] = __builtin_bit_cast(bf16x8, LA[abase + mi * 128 + ck]);
    __builtin_amdgcn_s_barrier();
    asm volatile("s_waitcnt lgkmcnt(0)" ::: "memory");
    __builtin_amdgcn_sched_barrier(0);  // rule 18: keep MFMA below the wait
    __builtin_amdgcn_s_setprio(1);
#pragma unroll
    for (int mi = 0; mi < 4; ++mi)
#pragma unroll
      for (int ni = 0; ni < 4; ++ni)
        acc[mi][ni] = __builtin_amdgcn_mfma_f32_16x16x32_bf16(af[mi], bfr[ni], acc[mi][ni], 0, 0, 0);
    __builtin_amdgcn_s_setprio(0);
    __builtin_amdgcn_s_barrier();

    // ---- phase 1: stage 3/6; read af[4..7]; counted vmcnt; MFMA mi 4..7
    gload_lds16(gA[3] + pk, &ldsA[stg * 2048 + t + 1536]);
    gload_lds16(gB[0] + pk, &ldsB[stg * 1024 + t]);
    gload_lds16(gB[1] + pk, &ldsB[stg * 1024 + t + 512]);
#pragma unroll
    for (int mi = 0; mi < 4; ++mi)
      af[mi] = __builtin_bit_cast(bf16x8, LA[abase + (4 + mi) * 128 + ck]);
    // outstanding: tile it+1 (6, oldest) + tile it+2 (6) -> wait it+1 landed
    asm volatile("s_waitcnt vmcnt(6)" ::: "memory");
    __builtin_amdgcn_s_barrier();
    asm volatile("s_waitcnt lgkmcnt(0)" ::: "memory");
    __builtin_amdgcn_sched_barrier(0);
    __builtin_amdgcn_s_setprio(1);
#pragma unroll
    for (int mi = 0; mi < 4; ++mi)
#pragma unroll
      for (int ni = 0; ni < 4; ++ni)
        acc[4 + mi][ni] = __builtin_amdgcn_mfma_f32_16x16x32_bf16(af[mi], bfr[ni], acc[4 + mi][ni], 0, 0, 0);
    __builtin_amdgcn_s_setprio(0);
    __builtin_amdgcn_s_barrier();

    cur = (cur == 2) ? 0 : cur + 1;
  }

  // ---- epilogue: drain tail DMA before reusing LDS as fp32 scratch
  asm volatile("s_waitcnt vmcnt(0)" ::: "memory");
  __builtin_amdgcn_s_barrier();

  // pair half-exchange: wave w and w^1 share one 128x64 output.
  // kh=0 keeps ni{0,1}, writes ni{2,3}; kh=1 keeps ni{2,3}, writes ni{0,1}.
  // scratch region per wave: 1024 f32x4 slots (16 KiB); 8 waves = 128 KiB.
  f32x4* scr = (f32x4*)lds;
  {
    f32x4* mw = scr + wave * 1024;
    if (kh == 0) {
#pragma unroll
      for (int mi = 0; mi < 8; ++mi)
#pragma unroll
        for (int nl = 0; nl < 2; ++nl)
          mw[(mi * 2 + nl) * 64 + lane] = acc[mi][2 + nl];
    } else {
#pragma unroll
      for (int mi = 0; mi < 8; ++mi)
#pragma unroll
        for (int nl = 0; nl < 2; ++nl)
          mw[(mi * 2 + nl) * 64 + lane] = acc[mi][nl];
    }
  }
  __syncthreads();
  {
    const f32x4* pw = scr + (wave ^ 1) * 1024;
    if (kh == 0) {
#pragma unroll
      for (int mi = 0; mi < 8; ++mi)
#pragma unroll
        for (int nl = 0; nl < 2; ++nl)
          acc[mi][nl] += pw[(mi * 2 + nl) * 64 + lane];
    } else {
#pragma unroll
      for (int mi = 0; mi < 8; ++mi)
#pragma unroll
        for (int nl = 0; nl < 2; ++nl)
          acc[mi][2 + nl] += pw[(mi * 2 + nl) * 64 + lane];
    }
  }

  // store: kh=0 -> cols [0,32), kh=1 -> cols [32,64) of the pair's 128x64 tile.
  // C/D layout: col=lane&15, row=(lane>>4)*4+reg
  const float* Ap = A + (size_t)g * S_N + bm + wm * 128;
  const float* Cp = C + (size_t)g * X_N + bn + wn * 64 + kh * 32;
  float cv[2];
#pragma unroll
  for (int nl = 0; nl < 2; ++nl) cv[nl] = Cp[nl * 16 + r];
#pragma unroll
  for (int mi = 0; mi < 8; ++mi) {
#pragma unroll
    for (int i = 0; i < 4; ++i) {
      int rowl = mi * 16 + q * 4 + i;
      float av = Ap[rowl];
      float* orow = logits + ((size_t)g * S_N + bm + wm * 128 + rowl) * X_N + bn + wn * 64 + kh * 32;
      if (kh == 0) {
        orow[r]      = acc[mi][0][i] - 0.5f * (av + cv[0]);
        orow[16 + r] = acc[mi][1][i] - 0.5f * (av + cv[1]);
      } else {
        orow[r]      = acc[mi][2][i] - 0.5f * (av + cv[0]);
        orow[16 + r] = acc[mi][3][i] - 0.5f * (av + cv[1]);
      }
    }
  }
}

// ---------------- P2: out[s] = LSE over (g,x) of (logits + const[g]) - log(X*G)
__global__ void k_lse(const float* __restrict__ logits, const float* __restrict__ constg,
                      float* __restrict__ out) {
  int s = blockIdx.x, t = threadIdx.x;
  float c0 = constg[0], c1 = constg[1];
  const float4* p0 = (const float4*)(logits + (size_t)s * X_N);
  const float4* p1 = (const float4*)(logits + ((size_t)S_N + s) * X_N);
  float4 v[4];
  v[0] = p0[t]; v[1] = p0[t + 256];
  v[2] = p1[t]; v[3] = p1[t + 256];
  v[0].x += c0; v[0].y += c0; v[0].z += c0; v[0].w += c0;
  v[1].x += c0; v[1].y += c0; v[1].z += c0; v[1].w += c0;
  v[2].x += c1; v[2].y += c1; v[2].z += c1; v[2].w += c1;
  v[3].x += c1; v[3].y += c1; v[3].z += c1; v[3].w += c1;

  float m = v[0].x;
#pragma unroll
  for (int j = 0; j < 4; ++j) {
    m = fmaxf(m, v[j].x); m = fmaxf(m, v[j].y);
    m = fmaxf(m, v[j].z); m = fmaxf(m, v[j].w);
  }
  for (int o = 32; o; o >>= 1) m = fmaxf(m, __shfl_xor(m, o));
  __shared__ float redm[4];
  __shared__ float reds[4];
  int w = t >> 6, l = t & 63;
  if (l == 0) redm[w] = m;
  __syncthreads();
  m = fmaxf(fmaxf(redm[0], redm[1]), fmaxf(redm[2], redm[3]));

  float sum = 0.f;
#pragma unroll
  for (int j = 0; j < 4; ++j) {
    sum += expf(v[j].x - m) + expf(v[j].y - m) + expf(v[j].z - m) + expf(v[j].w - m);
  }
  for (int o = 32; o; o >>= 1) sum += __shfl_xor(sum, o);
  if (l == 0) reds[w] = sum;
  __syncthreads();
  if (t == 0) {
    float tot = reds[0] + reds[1] + reds[2] + reds[3];
    out[s] = m + logf(tot) - 8.317766166719343f;  // log(4096)
  }
}

extern "C" void kernel_launch(void* const* d_in, const int* in_sizes, int n_in,
                              void* d_out, int out_size, void* d_ws, size_t ws_size,
                              hipStream_t stream) {
  const float* samples = (const float*)d_in[0];  // [S, F] fp32
  const float* xin     = (const float*)d_in[1];  // [X, F] fp32
  const float* stdv    = (const float*)d_in[2];  // [G, F] fp32
  float* out = (float*)d_out;                    // [S] fp32

  char* ws = (char*)d_ws;
  size_t off = 0;
  bf16* U = (bf16*)(ws + off);        off += (size_t)G_N * S_N * F_N * 2;  // 25.2 MB
  bf16* V = (bf16*)(ws + off);        off += (size_t)G_N * X_N * F_N * 2;  // 25.2 MB
  float* logits = (float*)(ws + off); off += (size_t)G_N * S_N * X_N * 4;  // 33.6 MB
  float* A = (float*)(ws + off);      off += (size_t)G_N * S_N * 4;
  float* C = (float*)(ws + off);      off += (size_t)G_N * X_N * 4;
  float* constg = (float*)(ws + off); off += 256;
  float* rinv = (float*)(ws + off);   off += (size_t)G_N * F_N * 4;

  k_const<<<dim3(G_N), dim3(256), 0, stream>>>(stdv, constg, rinv);
  k_prep<<<dim3(S_N + X_N), dim3(256), 0, stream>>>(samples, xin, rinv, U, V, A, C);
  k_gemm<<<dim3(X_N / TN, S_N / TM, G_N), dim3(512), 0, stream>>>(U, V, A, C, logits);
  k_lse<<<dim3(S_N), dim3(256), 0, stream>>>(logits, constg, out);
}